// Round 1
// baseline (225.935 us; speedup 1.0000x reference)
//
#include <hip/hip_runtime.h>
#include <hip/hip_bf16.h>

// ---- types ----
typedef __attribute__((ext_vector_type(8))) short short8_t;   // 8 x bf16 (4 VGPR)
typedef __attribute__((ext_vector_type(4))) float f32x4;      // MFMA acc

__device__ __forceinline__ short f2bf(float f) {
    union { float f; unsigned u; } v; v.f = f;
    unsigned r = (v.u + 0x7FFFu + ((v.u >> 16) & 1u)) >> 16;  // RNE
    return (short)r;
}

// Geometry: x[8][256][256][256] fp32. u = c in [0,128), v = c in [128,256).
// Rows: M = 8*128*256 = 262144 rows of 256 floats. Per-batch rows = 32768.
#define N_PER_BATCH 8388608.0f   // 128*256*256 elements per batch in v
#define LDW 264                  // padded LDS row (bf16 elems): +8 keeps 16B align, 2-way banks

// ---------------- kernel 1: per-block partial sums over v ----------------
// grid 2048 (256 blocks/batch), block 256. Each thread: 32 x float4 = 128 floats.
__global__ __launch_bounds__(256) void stats_partial(const float* __restrict__ x,
                                                     float2* __restrict__ partials) {
    int bid = blockIdx.x;
    int batch = bid >> 8;          // 256 blocks per batch
    int blk   = bid & 255;         // chunk of 32768 floats
    const float* base = x + ((size_t)batch << 24) + (1u << 23) + ((size_t)blk << 15);
    int tid = threadIdx.x;
    float s1 = 0.f, s2 = 0.f;
    #pragma unroll
    for (int i = 0; i < 32; ++i) {
        float4 v = *reinterpret_cast<const float4*>(base + (size_t)(i * 256 + tid) * 4);
        s1 += v.x + v.y + v.z + v.w;
        s2 += v.x * v.x + v.y * v.y + v.z * v.z + v.w * v.w;
    }
    #pragma unroll
    for (int off = 32; off; off >>= 1) {
        s1 += __shfl_down(s1, off);
        s2 += __shfl_down(s2, off);
    }
    __shared__ float2 red[4];
    if ((tid & 63) == 0) red[tid >> 6] = make_float2(s1, s2);
    __syncthreads();
    if (tid == 0) {
        float a1 = 0.f, a2 = 0.f;
        #pragma unroll
        for (int w = 0; w < 4; ++w) { a1 += red[w].x; a2 += red[w].y; }
        partials[bid] = make_float2(a1, a2);
    }
}

// ---------------- kernel 1b: finalize per-batch mean/rstd ----------------
// grid 8, block 256 (one thread per partial).
__global__ __launch_bounds__(256) void stats_final(const float2* __restrict__ partials,
                                                   float2* __restrict__ stats) {
    int batch = blockIdx.x;
    int tid = threadIdx.x;
    float2 p = partials[(batch << 8) + tid];
    float s1 = p.x, s2 = p.y;
    #pragma unroll
    for (int off = 32; off; off >>= 1) {
        s1 += __shfl_down(s1, off);
        s2 += __shfl_down(s2, off);
    }
    __shared__ float2 red[4];
    if ((tid & 63) == 0) red[tid >> 6] = make_float2(s1, s2);
    __syncthreads();
    if (tid == 0) {
        float a1 = 0.f, a2 = 0.f;
        #pragma unroll
        for (int w = 0; w < 4; ++w) { a1 += red[w].x; a2 += red[w].y; }
        float mean = a1 / N_PER_BATCH;
        float var  = a2 / N_PER_BATCH - mean * mean;
        stats[batch] = make_float2(mean, rsqrtf(var + 1e-5f));
    }
}

// ---------------- kernel 2: fused normalize + GEMM + gate ----------------
// W (bf16) fully in LDS. 1024 threads = 16 waves; each wave owns 16-row tiles.
// Per tile: A-frags (normalized v, bf16) in regs, loop nc over 16 col-tiles,
// 8 MFMAs each, epilogue out = u * (acc + b[col] + 1).
__global__ __launch_bounds__(1024, 4) void fused_gemm(const float* __restrict__ x,
                                                      const float* __restrict__ W,
                                                      const float* __restrict__ bias,
                                                      const float2* __restrict__ stats,
                                                      float* __restrict__ out) {
    __shared__ short Wlds[256 * LDW];   // 135168 B
    int tid = threadIdx.x;

    // Stage W fp32 -> bf16 into LDS. 65536 elems = 16384 float4; 16 per thread.
    #pragma unroll
    for (int i = 0; i < 16; ++i) {
        int idx4 = tid + (i << 10);
        int row = idx4 >> 6;            // 64 float4 per 256-elem row
        int c0  = (idx4 & 63) << 2;
        float4 w4 = reinterpret_cast<const float4*>(W)[idx4];
        short4 s;
        s.x = f2bf(w4.x); s.y = f2bf(w4.y); s.z = f2bf(w4.z); s.w = f2bf(w4.w);
        *reinterpret_cast<short4*>(&Wlds[row * LDW + c0]) = s;
    }
    __syncthreads();

    int wid  = tid >> 6;
    int lane = tid & 63;
    int l15  = lane & 15;
    int l4   = lane >> 4;

    int gw = (blockIdx.x << 4) + wid;   // global wave id, 0..4095
    const int nTiles = 16384;           // 262144 rows / 16

    for (int tile = gw; tile < nTiles; tile += 4096) {
        int row0 = tile << 4;
        int b_i  = row0 >> 15;          // batch (tiles never cross batches)
        int cg0  = row0 & 32767;
        const float* vbase = x + ((size_t)b_i << 24) + (1u << 23) + ((size_t)cg0 << 8);
        const float* ubase = x + ((size_t)b_i << 24) + ((size_t)cg0 << 8);
        float*       obase = out + ((size_t)row0 << 8);
        float2 ms = stats[b_i];
        float mean = ms.x, rstd = ms.y;

        // A fragments: lane supplies A[l15][kb*32 + l4*8 + j], j=0..7
        short8_t af[8];
        const float* arow = vbase + (size_t)l15 * 256 + (l4 << 3);
        #pragma unroll
        for (int kb = 0; kb < 8; ++kb) {
            float4 p0 = *reinterpret_cast<const float4*>(arow + kb * 32);
            float4 p1 = *reinterpret_cast<const float4*>(arow + kb * 32 + 4);
            short8_t a;
            a[0] = f2bf((p0.x - mean) * rstd);
            a[1] = f2bf((p0.y - mean) * rstd);
            a[2] = f2bf((p0.z - mean) * rstd);
            a[3] = f2bf((p0.w - mean) * rstd);
            a[4] = f2bf((p1.x - mean) * rstd);
            a[5] = f2bf((p1.y - mean) * rstd);
            a[6] = f2bf((p1.z - mean) * rstd);
            a[7] = f2bf((p1.w - mean) * rstd);
            af[kb] = a;
        }

        #pragma unroll 2
        for (int nc = 0; nc < 16; ++nc) {
            int col = (nc << 4) + l15;
            const short* wrow = &Wlds[col * LDW + (l4 << 3)];
            f32x4 acc = {0.f, 0.f, 0.f, 0.f};
            #pragma unroll
            for (int kb = 0; kb < 8; ++kb) {
                short8_t bf = *reinterpret_cast<const short8_t*>(wrow + kb * 32);
                acc = __builtin_amdgcn_mfma_f32_16x16x32_bf16(af[kb], bf, acc, 0, 0, 0);
            }
            float bp1 = bias[col] + 1.0f;
            int rbase = l4 << 2;
            #pragma unroll
            for (int r = 0; r < 4; ++r) {
                int off = ((rbase + r) << 8) + col;   // C/D: row=(lane>>4)*4+r, col=lane&15
                float uv = ubase[off];
                obase[off] = uv * (acc[r] + bp1);
            }
        }
    }
}

extern "C" void kernel_launch(void* const* d_in, const int* in_sizes, int n_in,
                              void* d_out, int out_size, void* d_ws, size_t ws_size,
                              hipStream_t stream) {
    const float* x    = (const float*)d_in[0];
    const float* W    = (const float*)d_in[1];
    const float* bias = (const float*)d_in[2];
    float* out = (float*)d_out;

    float2* partials = (float2*)d_ws;                       // 2048 * 8 B = 16 KB
    float2* stats    = (float2*)((char*)d_ws + 16384);      // 8 * 8 B

    stats_partial<<<2048, 256, 0, stream>>>(x, partials);
    stats_final<<<8, 256, 0, stream>>>(partials, stats);
    fused_gemm<<<256, 1024, 0, stream>>>(x, W, bias, stats, out);
}

// Round 2
// 215.674 us; speedup vs baseline: 1.0476x; 1.0476x over previous
//
#include <hip/hip_runtime.h>
#include <hip/hip_bf16.h>

// ---- types ----
typedef __attribute__((ext_vector_type(8))) short short8_t;   // 8 x bf16 (4 VGPR)
typedef __attribute__((ext_vector_type(4))) float f32x4;      // MFMA acc

__device__ __forceinline__ short f2bf(float f) {
    union { float f; unsigned u; } v; v.f = f;
    unsigned r = (v.u + 0x7FFFu + ((v.u >> 16) & 1u)) >> 16;  // RNE
    return (short)r;
}

// Geometry: x[8][256][256][256] fp32. u = c in [0,128), v = c in [128,256).
// Rows: M = 8*128*256 = 262144 rows of 256 floats. Per-batch rows = 32768.
#define N_PER_BATCH 8388608.0f   // 128*256*256 elements per batch in v
#define LDR 264                  // padded LDS tile row (bf16): A-reads 2-way banks (free)

// ---------------- kernel 1: per-block partial sums over v ----------------
__global__ __launch_bounds__(256) void stats_partial(const float* __restrict__ x,
                                                     float2* __restrict__ partials) {
    int bid = blockIdx.x;
    int batch = bid >> 8;
    int blk   = bid & 255;
    const float* base = x + ((size_t)batch << 24) + (1u << 23) + ((size_t)blk << 15);
    int tid = threadIdx.x;
    float s1 = 0.f, s2 = 0.f;
    #pragma unroll
    for (int i = 0; i < 32; ++i) {
        float4 v = *reinterpret_cast<const float4*>(base + (size_t)(i * 256 + tid) * 4);
        s1 += v.x + v.y + v.z + v.w;
        s2 += v.x * v.x + v.y * v.y + v.z * v.z + v.w * v.w;
    }
    #pragma unroll
    for (int off = 32; off; off >>= 1) {
        s1 += __shfl_down(s1, off);
        s2 += __shfl_down(s2, off);
    }
    __shared__ float2 red[4];
    if ((tid & 63) == 0) red[tid >> 6] = make_float2(s1, s2);
    __syncthreads();
    if (tid == 0) {
        float a1 = 0.f, a2 = 0.f;
        #pragma unroll
        for (int w = 0; w < 4; ++w) { a1 += red[w].x; a2 += red[w].y; }
        partials[bid] = make_float2(a1, a2);
    }
}

// ---------------- kernel 1b: finalize per-batch mean/rstd ----------------
__global__ __launch_bounds__(256) void stats_final(const float2* __restrict__ partials,
                                                   float2* __restrict__ stats) {
    int batch = blockIdx.x;
    int tid = threadIdx.x;
    float2 p = partials[(batch << 8) + tid];
    float s1 = p.x, s2 = p.y;
    #pragma unroll
    for (int off = 32; off; off >>= 1) {
        s1 += __shfl_down(s1, off);
        s2 += __shfl_down(s2, off);
    }
    __shared__ float2 red[4];
    if ((tid & 63) == 0) red[tid >> 6] = make_float2(s1, s2);
    __syncthreads();
    if (tid == 0) {
        float a1 = 0.f, a2 = 0.f;
        #pragma unroll
        for (int w = 0; w < 4; ++w) { a1 += red[w].x; a2 += red[w].y; }
        float mean = a1 / N_PER_BATCH;
        float var  = a2 / N_PER_BATCH - mean * mean;
        stats[batch] = make_float2(mean, rsqrtf(var + 1e-5f));
    }
}

// ---------------- kernel 2: fused normalize + GEMM + gate ----------------
// Block = 16 waves. Wave w holds B-frags for cols [w*16, w*16+16) in regs.
// Per 16-row tile: block stages normalized bf16 v into double-buffered LDS
// (reg-staged: global float4 -> cvt -> ds_write), each wave does 8 MFMAs,
// 4x4 shuffle-transpose epilogue -> float4 u-load / out-store.
__global__ __launch_bounds__(1024, 4) void fused_gemm(const float* __restrict__ x,
                                                      const float* __restrict__ W,
                                                      const float* __restrict__ bias,
                                                      const float2* __restrict__ stats,
                                                      float* __restrict__ out) {
    __shared__ short vt[2][16 * LDR];   // 2 x 8448 shorts = 33792 B
    const int tid  = threadIdx.x;
    const int wid  = tid >> 6;
    const int lane = tid & 63;
    const int l15  = lane & 15;
    const int l4   = lane >> 4;
    const int q    = l15 & 3;
    const int qg   = l15 >> 2;

    const int bi = blockIdx.x >> 5;          // 32 blocks per batch
    const float2 ms = stats[bi];
    const float mean = ms.x, rstd = ms.y;

    // ---- B fragments: W[col][k], col = wid*16 + l15, k = kb*32 + l4*8 + j ----
    short8_t bfrag[8];
    {
        const float* wbase = W + (size_t)(wid * 16 + l15) * 256 + (l4 << 3);
        #pragma unroll
        for (int kb = 0; kb < 8; ++kb) {
            float4 p0 = *reinterpret_cast<const float4*>(wbase + kb * 32);
            float4 p1 = *reinterpret_cast<const float4*>(wbase + kb * 32 + 4);
            short8_t s;
            s[0] = f2bf(p0.x); s[1] = f2bf(p0.y); s[2] = f2bf(p0.z); s[3] = f2bf(p0.w);
            s[4] = f2bf(p1.x); s[5] = f2bf(p1.y); s[6] = f2bf(p1.z); s[7] = f2bf(p1.w);
            bfrag[kb] = s;
        }
    }
    // bias (+1) for this lane's post-transpose cols: wid*16 + qg*4 + (0..3)
    float4 bq = *reinterpret_cast<const float4*>(bias + wid * 16 + (qg << 2));
    bq.x += 1.f; bq.y += 1.f; bq.z += 1.f; bq.w += 1.f;

    // ---- block's row range: 64 tiles x 16 rows = 1024 rows, never crosses batch ----
    const size_t row0 = (size_t)blockIdx.x << 10;
    const float* vbase = x + ((size_t)bi << 24) + (1u << 23) + ((row0 & 32767) << 8);
    const float* ubase = x + ((size_t)bi << 24) + ((row0 & 32767) << 8);
    float*       obase = out + (row0 << 8);

    // staging role: thread -> tile-local (row = tid>>6, col = (tid&63)*4)
    const int   srow = tid >> 6;
    const int   scol = (tid & 63) << 2;
    const size_t goff = (size_t)srow * 256 + scol;
    const int   lds_w = srow * LDR + scol;

    // per-wave epilogue offset within tile: row = l4*4+q, colgroup = wid*16+qg*4
    const size_t eoff = (size_t)(l4 * 4 + q) * 256 + wid * 16 + (qg << 2);

    // A-frag LDS byte base: row = l15, k-offset = l4*8
    const int aoff = l15 * LDR + (l4 << 3);

    // ---- prologue: stage tile 0 ----
    {
        float4 v0 = *reinterpret_cast<const float4*>(vbase + goff);
        short4 s;
        s.x = f2bf((v0.x - mean) * rstd); s.y = f2bf((v0.y - mean) * rstd);
        s.z = f2bf((v0.z - mean) * rstd); s.w = f2bf((v0.w - mean) * rstd);
        *reinterpret_cast<short4*>(&vt[0][lds_w]) = s;
    }
    __syncthreads();

    for (int t = 0; t < 64; ++t) {
        const int cur = t & 1;
        // issue next tile's v load early (clamped; t=63 redundantly reloads 63)
        const int tn = (t < 63) ? t + 1 : 63;
        float4 vn = *reinterpret_cast<const float4*>(vbase + ((size_t)tn << 12) + goff);
        // issue u load early
        const size_t uo = ((size_t)t << 12) + eoff;
        float4 u4 = *reinterpret_cast<const float4*>(ubase + uo);

        // ---- MFMA over K=256 ----
        f32x4 acc = {0.f, 0.f, 0.f, 0.f};
        #pragma unroll
        for (int kb = 0; kb < 8; ++kb) {
            short8_t a = *reinterpret_cast<const short8_t*>(&vt[cur][aoff + kb * 32]);
            acc = __builtin_amdgcn_mfma_f32_16x16x32_bf16(a, bfrag[kb], acc, 0, 0, 0);
        }

        // ---- 4x4 transpose within lane quads: reg r <-> lane q ----
        float v0 = acc[0], v1 = acc[1], v2 = acc[2], v3 = acc[3];
        float s0 = __shfl_xor(v1, 1), s1 = __shfl_xor(v0, 1);
        float s2 = __shfl_xor(v3, 1), s3 = __shfl_xor(v2, 1);
        const bool qb0 = (q & 1);
        float w0 = qb0 ? s0 : v0;
        float w1 = qb0 ? v1 : s1;
        float w2 = qb0 ? s2 : v2;
        float w3 = qb0 ? v3 : s3;
        float t0 = __shfl_xor(w2, 2), t1 = __shfl_xor(w3, 2);
        float t2 = __shfl_xor(w0, 2), t3 = __shfl_xor(w1, 2);
        const bool qb1 = (q & 2);
        float x0 = qb1 ? t0 : w0;
        float x1 = qb1 ? t1 : w1;
        float x2 = qb1 ? w2 : t2;
        float x3 = qb1 ? w3 : t3;

        // ---- epilogue: out = u * (y + b + 1) ----
        float4 o;
        o.x = u4.x * (x0 + bq.x);
        o.y = u4.y * (x1 + bq.y);
        o.z = u4.z * (x2 + bq.z);
        o.w = u4.w * (x3 + bq.w);
        *reinterpret_cast<float4*>(obase + uo) = o;

        // ---- stage next tile into other buffer ----
        short4 sn;
        sn.x = f2bf((vn.x - mean) * rstd); sn.y = f2bf((vn.y - mean) * rstd);
        sn.z = f2bf((vn.z - mean) * rstd); sn.w = f2bf((vn.w - mean) * rstd);
        *reinterpret_cast<short4*>(&vt[cur ^ 1][lds_w]) = sn;
        __syncthreads();
    }
}

extern "C" void kernel_launch(void* const* d_in, const int* in_sizes, int n_in,
                              void* d_out, int out_size, void* d_ws, size_t ws_size,
                              hipStream_t stream) {
    const float* x    = (const float*)d_in[0];
    const float* W    = (const float*)d_in[1];
    const float* bias = (const float*)d_in[2];
    float* out = (float*)d_out;

    float2* partials = (float2*)d_ws;                       // 2048 * 8 B
    float2* stats    = (float2*)((char*)d_ws + 16384);      // 8 * 8 B

    stats_partial<<<2048, 256, 0, stream>>>(x, partials);
    stats_final<<<8, 256, 0, stream>>>(partials, stats);
    fused_gemm<<<256, 1024, 0, stream>>>(x, W, bias, stats, out);
}